// Round 5
// baseline (233.528 us; speedup 1.0000x reference)
//
#include <hip/hip_runtime.h>

// GCNFast: out[b,s,t,d] = relu( sum_j relu(AA[i%64,j%64]*GCW[i,j]) * X[j,b,d] + GCB[i,d] )
// Sparsity: AA (64x64, ~50% dense) -> per row-group s, support supp(s) in c.
// K reordered kk=c*64+t; A' compact [s*64+tt][ci*64+t], XT' [b*128+d][c*64+t].
// gemm skips zero c-tiles (nt[s]~32 of 64).
// Round-5: OCCUPANCY fix. gemm GBN 256->128, 512 thr / 8 waves, LDS 2x24KB=48KB
//   -> 3 blocks/CU (24 waves/CU vs round-4's 4). Same proven dbuf counted-vmcnt
//   loop (vmcnt(3), 2 barriers/tile). np=bid&15 == batch b; XCD-affine.
// prep A-part: direct global gather (L1-served, stride-256B) replaces the
//   8-way-bank-conflicted LDS row transpose; coalesced short8 writes.
// Fallback to fused single-kernel path if ws too small.

#define NC 64
#define NS 64
#define NT 64
#define DH 128
#define BATCH 16
#define MDIM 4096
#define KDIM 4096
#define KPAD 4096
#define TM 128
#define TK 64
#define GBM 64
#define GBN 128
#define GBK 64

typedef __attribute__((ext_vector_type(8))) short short8;
typedef __attribute__((ext_vector_type(4))) short short4v;
typedef __attribute__((ext_vector_type(4))) float floatx4;

__device__ __forceinline__ unsigned short f2bf(float f) {
    union { float f; unsigned int i; } v; v.f = f;
    return (unsigned short)((v.i + 0x7fffu + ((v.i >> 16) & 1u)) >> 16);
}
__device__ __forceinline__ void async16(const void* g, void* l) {
    __builtin_amdgcn_global_load_lds(
        (const __attribute__((address_space(1))) void*)g,
        (__attribute__((address_space(3))) void*)l, 16, 0, 0);
}

// ---- fused prep ----
// blocks [0,4096): A'[r=s*64+tt][ci*64+t] = relu(GCW[tt*64+s][t*64+cidx[s][ci]])
//   via DIRECT global gather (8 x stride-256B scalar loads per thread, L1-served)
//   -> coalesced 16B store. tt==0 blocks publish cidx[s][.], ns[s].
// blocks [4096,5120): XT'[b*128+d][c*64+t] = bf16(h[b,c,t,d]) via LDS transpose.
__global__ __launch_bounds__(256)
void prep(const float* __restrict__ aam, const float* __restrict__ gcw,
          const float* __restrict__ hmat,
          unsigned short* __restrict__ Abf, unsigned short* __restrict__ XT,
          unsigned short* __restrict__ cidx, int* __restrict__ nsb)
{
    const int tid = threadIdx.x;
    if ((int)blockIdx.x < MDIM) {
        const int r  = blockIdx.x;
        const int s  = r >> 6;
        const int tt = r & 63;
        const int i  = tt * 64 + s;
        __shared__ unsigned short scidx[64];
        __shared__ int sns;
        if (tid < 64) {
            float v = aam[(size_t)s * KDIM + tid];
            unsigned long long m = __ballot(v != 0.f);
            int rank = __popcll(m & ((1ull << tid) - 1ull));
            if (v != 0.f) scidx[rank] = (unsigned short)tid;
            if (tid == 0) sns = (int)__popcll(m);
            if (tt == 0) {
                if (v != 0.f) cidx[s * 64 + rank] = (unsigned short)tid;
                if (tid == 0) nsb[s] = (int)__popcll(m);
            }
        }
        __syncthreads();
        const int ke = sns * 64;   // multiple of 64
        const float* gr = gcw + (size_t)i * KDIM;
        for (int kk0 = tid * 8; kk0 < ke; kk0 += 2048) {
            const int c  = (int)scidx[kk0 >> 6];
            const int t0 = kk0 & 63;   // multiple of 8
            short8 p;
#pragma unroll
            for (int e = 0; e < 8; ++e) {
                float v = gr[(t0 + e) * 64 + c];
                v = v > 0.f ? v : 0.f;
                p[e] = (short)f2bf(v);
            }
            *(short8*)(Abf + (size_t)r * KPAD + kk0) = p;
        }
    } else {
        const int blk = blockIdx.x - MDIM;
        const int b = blk >> 6;
        const int c = blk & 63;
        __shared__ unsigned short sx[64][136];
        const float* hp = hmat + (((size_t)b * NC + c) * NT) * DH;
#pragma unroll
        for (int u = 0; u < 8; ++u) {
            const int idx = u * 1024 + tid * 4;   // float idx in [64t][128d]
            const int t = idx >> 7;
            const int d = idx & 127;
            floatx4 v = *(const floatx4*)(hp + idx);
            short4v p;
#pragma unroll
            for (int e = 0; e < 4; ++e) p[e] = (short)f2bf(v[e]);
            *(short4v*)&sx[t][d] = p;
        }
        __syncthreads();
        const int d  = tid >> 1;
        const int th = (tid & 1) * 32;
        unsigned short* dst = XT + ((size_t)(b * DH + d)) * KPAD + c * 64 + th;
#pragma unroll
        for (int u2 = 0; u2 < 4; ++u2) {
            short8 p;
#pragma unroll
            for (int e = 0; e < 8; ++e)
                p[e] = (short)sx[th + u2 * 8 + e][d];
            *(short8*)(dst + u2 * 8) = p;
        }
    }
}

// ---- GEMM: per-(s, batch) tile C[64, 128], K over ns[s] nonzero c-tiles ----
__global__ __launch_bounds__(512, 6)
void gemm(const unsigned short* __restrict__ Abf,
          const unsigned short* __restrict__ XT,
          const unsigned short* __restrict__ cidx,
          const int* __restrict__ nsb,
          const float* __restrict__ gcb,
          float* __restrict__ out)
{
    __shared__ short lds[2][(GBM + GBN) * GBK];   // 2 x 24 KB = 48 KB -> 3 blocks/CU

    const int tid = threadIdx.x;
    const int bid = blockIdx.x;
    const int np = bid & 15;       // n-panel == batch b (128 cols); XCD = bid&7
    const int s  = bid >> 4;       // row-group 0..63
    const int n0 = np * GBN;

    const int lane = tid & 63;
    const int w    = tid >> 6;     // 0..7
    const int wm   = (w >> 2) * 32;   // 2 M-wave rows
    const int wn   = (w & 3) * 32;    // 4 N-wave cols
    const int l15  = lane & 15;
    const int q    = lane >> 4;
    const int srow = lane >> 3;
    const int swz  = ((lane & 7) ^ srow) << 3;   // swizzled k-chunk (elements)

    const int nt = nsb[s];                        // K-tiles = |supp(s)|
    const int cl = (int)cidx[s * 64 + lane];      // lane t holds c(t) (t<nt valid)

    const unsigned short* Ab = Abf + (size_t)(s * 64) * KPAD + swz;
    const unsigned short* Xb = XT  + (size_t)n0 * KPAD + swz;

    floatx4 acc[2][2];
#pragma unroll
    for (int mi = 0; mi < 2; ++mi)
#pragma unroll
        for (int ni = 0; ni < 2; ++ni)
            acc[mi][ni] = (floatx4){0.f, 0.f, 0.f, 0.f};

    // 3 global_load_lds per wave per tile (1 A-group + 2 X-groups)
    auto stage = [&](int t, int b) {
        short* dst = lds[b];
        const int c = __shfl(cl, t);
        const size_t ka = (size_t)t * GBK;   // A' compact k-offset
        const size_t kx = (size_t)c * GBK;   // XT' reordered k-offset
        async16(Ab + (size_t)(w * 8 + srow) * KPAD + ka,       dst + (w * 8) * GBK);
        async16(Xb + (size_t)(w * 8 + srow) * KPAD + kx,       dst + (GBM + w * 8) * GBK);
        async16(Xb + (size_t)(64 + w * 8 + srow) * KPAD + kx,  dst + (GBM + 64 + w * 8) * GBK);
    };

    auto compute = [&](int b) {
        const short* sA = lds[b];
        const short* sX = lds[b] + GBM * GBK;
#pragma unroll
        for (int h2 = 0; h2 < 2; ++h2) {
            const int co = ((h2 * 4 + q) ^ (l15 & 7)) << 3;
            short8 af[2], xf[2];
#pragma unroll
            for (int mi = 0; mi < 2; ++mi)
                af[mi] = *(const short8*)&sA[(wm + mi * 16 + l15) * GBK + co];
#pragma unroll
            for (int ni = 0; ni < 2; ++ni)
                xf[ni] = *(const short8*)&sX[(wn + ni * 16 + l15) * GBK + co];
            __builtin_amdgcn_s_setprio(1);
#pragma unroll
            for (int mi = 0; mi < 2; ++mi)
#pragma unroll
                for (int ni = 0; ni < 2; ++ni)
                    acc[mi][ni] = __builtin_amdgcn_mfma_f32_16x16x32_bf16(
                        af[mi], xf[ni], acc[mi][ni], 0, 0, 0);
            __builtin_amdgcn_s_setprio(0);
        }
    };

    if (nt > 0) stage(0, 0);
    if (nt > 1) stage(1, 1);
    for (int t = 0; t < nt - 1; ++t) {
        // t's 3 loads retired; (t+1)'s 3 stay in flight
        asm volatile("s_waitcnt vmcnt(3)" ::: "memory");
        __builtin_amdgcn_s_barrier();
        compute(t & 1);
        __builtin_amdgcn_s_barrier();
        if (t + 2 < nt) stage(t + 2, t & 1);
    }
    if (nt > 0) {
        asm volatile("s_waitcnt vmcnt(0)" ::: "memory");
        __builtin_amdgcn_s_barrier();
        compute((nt - 1) & 1);
    }

    // epilogue: row-in-tile tt -> original i = tt*64 + s; out[np, s, tt, d]
#pragma unroll
    for (int mi = 0; mi < 2; ++mi) {
        const int tt0 = wm + mi * 16 + q * 4;
#pragma unroll
        for (int ni = 0; ni < 2; ++ni) {
            const int d = wn + ni * 16 + l15;      // 0..127 == dh index
#pragma unroll
            for (int r = 0; r < 4; ++r) {
                const int tt = tt0 + r;
                const int i  = tt * 64 + s;
                float v = acc[mi][ni][r] + gcb[(size_t)i * DH + d];
                v = v > 0.f ? v : 0.f;
                out[(((size_t)np * NS + s) * NT + tt) * DH + d] = v;
            }
        }
    }
}

// ---- fallback: fused kernel (used only if ws too small) ----
#define APAD 40
#define XPAD 20
__global__ __launch_bounds__(256, 2)
void gcn_fused(const float* __restrict__ hmat, const float* __restrict__ aam,
               const float* __restrict__ gcw, const float* __restrict__ gcb,
               float* __restrict__ out)
{
    __shared__ short sA[TM * APAD];
    __shared__ unsigned int sX[DH * XPAD];
    const int tid = threadIdx.x;
    const int bid = blockIdx.x;
    const int mp  = (bid & 7) * 4 + (bid >> 7);
    const int b   = (bid >> 3) & 15;
    const int i0  = mp * TM;
    const int lane = tid & 63;
    const int wm = ((tid >> 6) >> 1) * 64;
    const int wn = ((tid >> 6) & 1) * 64;
    const int l15 = lane & 15;
    const int q   = lane >> 4;
    floatx4 acc[4][4];
#pragma unroll
    for (int mi = 0; mi < 4; ++mi)
#pragma unroll
        for (int ni = 0; ni < 4; ++ni) acc[mi][ni] = (floatx4){0.f,0.f,0.f,0.f};
    const int ar = tid >> 2, ac = (tid & 3) << 3;
    const int kp = tid >> 4, dg = (tid & 15) << 3;
    const int wkey = (tid & 3) << 2;
    for (int k0 = 0; k0 < KDIM; k0 += 32) {
        const size_t ga0 = (size_t)(i0 + ar) * KDIM + (k0 + ac);
        const size_t ga1 = ga0 + (size_t)64 * KDIM;
        floatx4 aa0a = *(const floatx4*)(aam + ga0), aa0b = *(const floatx4*)(aam + ga0 + 4);
        floatx4 ww0a = *(const floatx4*)(gcw + ga0), ww0b = *(const floatx4*)(gcw + ga0 + 4);
        floatx4 aa1a = *(const floatx4*)(aam + ga1), aa1b = *(const floatx4*)(aam + ga1 + 4);
        floatx4 ww1a = *(const floatx4*)(gcw + ga1), ww1b = *(const floatx4*)(gcw + ga1 + 4);
        const int jj = k0 + 2 * kp, tt = jj >> 6, cc = jj & 63;
        const size_t gx0 = ((size_t)(b * NC + cc) * NT + tt) * DH + dg;
        const size_t gx1 = gx0 + (size_t)NT * DH;
        floatx4 x0a = *(const floatx4*)(hmat + gx0), x0b = *(const floatx4*)(hmat + gx0 + 4);
        floatx4 x1a = *(const floatx4*)(hmat + gx1), x1b = *(const floatx4*)(hmat + gx1 + 4);
        __syncthreads();
        short8 p0, p1;
#pragma unroll
        for (int e = 0; e < 4; ++e) {
            float v0 = aa0a[e]*ww0a[e]; v0 = v0>0.f?v0:0.f;
            float v1 = aa0b[e]*ww0b[e]; v1 = v1>0.f?v1:0.f;
            float v2 = aa1a[e]*ww1a[e]; v2 = v2>0.f?v2:0.f;
            float v3 = aa1b[e]*ww1b[e]; v3 = v3>0.f?v3:0.f;
            p0[e] = (short)f2bf(v0); p0[e+4] = (short)f2bf(v1);
            p1[e] = (short)f2bf(v2); p1[e+4] = (short)f2bf(v3);
        }
        *(short8*)&sA[ar * APAD + ac] = p0;
        *(short8*)&sA[(ar + 64) * APAD + ac] = p1;
#pragma unroll
        for (int e = 0; e < 4; ++e) {
            unsigned int pka = (unsigned int)f2bf(x0a[e]) | ((unsigned int)f2bf(x1a[e]) << 16);
            unsigned int pkb = (unsigned int)f2bf(x0b[e]) | ((unsigned int)f2bf(x1b[e]) << 16);
            sX[(dg + e) * XPAD + (kp ^ wkey)] = pka;
            sX[(dg + e + 4) * XPAD + (kp ^ wkey)] = pkb;
        }
        __syncthreads();
        short8 afrag[4], bfrag[4];
#pragma unroll
        for (int mi = 0; mi < 4; ++mi)
            afrag[mi] = *(const short8*)&sA[(wm + mi * 16 + l15) * APAD + q * 8];
#pragma unroll
        for (int ni = 0; ni < 4; ++ni) {
            const int row = wn + ni * 16 + l15;
            const int col = (q * 4) ^ (((row >> 3) & 3) << 2);
            bfrag[ni] = *(const short8*)(sX + row * XPAD + col);
        }
#pragma unroll
        for (int mi = 0; mi < 4; ++mi)
#pragma unroll
            for (int ni = 0; ni < 4; ++ni)
                acc[mi][ni] = __builtin_amdgcn_mfma_f32_16x16x32_bf16(
                    afrag[mi], bfrag[ni], acc[mi][ni], 0, 0, 0);
    }
#pragma unroll
    for (int mi = 0; mi < 4; ++mi) {
        const int ibase = i0 + wm + mi * 16 + q * 4;
#pragma unroll
        for (int ni = 0; ni < 4; ++ni) {
            const int d = wn + ni * 16 + l15;
#pragma unroll
            for (int r = 0; r < 4; ++r) {
                const int i = ibase + r;
                float v = acc[mi][ni][r] + gcb[(size_t)i * DH + d];
                v = v > 0.f ? v : 0.f;
                out[(((size_t)b * NS + (i & 63)) * NT + (i >> 6)) * DH + d] = v;
            }
        }
    }
}

extern "C" void kernel_launch(void* const* d_in, const int* in_sizes, int n_in,
                              void* d_out, int out_size, void* d_ws, size_t ws_size,
                              hipStream_t stream) {
    const float* h   = (const float*)d_in[0];
    const float* aam = (const float*)d_in[2];
    const float* gcw = (const float*)d_in[3];
    const float* gcb = (const float*)d_in[4];
    float* out = (float*)d_out;

    const size_t A_BYTES   = (size_t)MDIM * KPAD * 2;            // 33.55 MB
    const size_t XT_BYTES  = (size_t)BATCH * DH * KPAD * 2;      // 16.78 MB
    const size_t IDX_BYTES = 64 * 64 * 2;                        // 8 KB
    const size_t NS_BYTES  = 64 * 4;

    if (ws_size >= A_BYTES + XT_BYTES + IDX_BYTES + NS_BYTES) {
        unsigned short* Abf = (unsigned short*)d_ws;
        unsigned short* XTp = (unsigned short*)((char*)d_ws + A_BYTES);
        unsigned short* cid = (unsigned short*)((char*)d_ws + A_BYTES + XT_BYTES);
        int* nsb            = (int*)((char*)d_ws + A_BYTES + XT_BYTES + IDX_BYTES);
        prep<<<dim3(MDIM + BATCH * NT), 256, 0, stream>>>(aam, gcw, h, Abf, XTp, cid, nsb);
        gemm<<<dim3(64 * 16), 512, 0, stream>>>(Abf, XTp, cid, nsb, gcb, out);
    } else {
        gcn_fused<<<dim3((MDIM / TM) * BATCH), 256, 0, stream>>>(h, aam, gcw, gcb, out);
    }
}